// Round 2
// baseline (1603.684 us; speedup 1.0000x reference)
//
#include <hip/hip_runtime.h>
#include <hip/hip_bf16.h>

#define T_TOK 8192
#define D_DIM 1024
#define F_DIM 4096
#define NE 8

#define BM 128
#define BN 128
#define BK 32

typedef _Float16 v8h __attribute__((ext_vector_type(8)));
typedef float f32x4 __attribute__((ext_vector_type(4)));

__device__ __forceinline__ void async_lds16(void* lds, const void* g) {
    __builtin_amdgcn_global_load_lds(
        (const __attribute__((address_space(1))) void*)g,
        (__attribute__((address_space(3))) void*)lds,
        16, 0, 0);
}

// ---------------- router: logits -> top2 -> scatter ----------------
__global__ void router_kernel(const float* __restrict__ x,
                              const float* __restrict__ Wgate,
                              int* __restrict__ cnt,
                              int* __restrict__ rows,
                              float* __restrict__ wts) {
    int t = blockIdx.x;
    int lane = threadIdx.x;
    const float* xr = x + (size_t)t * D_DIM;
    float acc[NE];
#pragma unroll
    for (int e = 0; e < NE; ++e) acc[e] = 0.f;
#pragma unroll
    for (int i = 0; i < D_DIM / 64; ++i) {
        int d = i * 64 + lane;
        float xv = xr[d];
#pragma unroll
        for (int e = 0; e < NE; ++e) acc[e] += xv * Wgate[e * D_DIM + d];
    }
#pragma unroll
    for (int off = 32; off > 0; off >>= 1) {
#pragma unroll
        for (int e = 0; e < NE; ++e) acc[e] += __shfl_xor(acc[e], off, 64);
    }
    if (lane == 0) {
        int e0 = 0;
#pragma unroll
        for (int e = 1; e < NE; ++e) if (acc[e] > acc[e0]) e0 = e;
        int e1 = (e0 == 0) ? 1 : 0;
#pragma unroll
        for (int e = 0; e < NE; ++e) if (e != e0 && acc[e] > acc[e1]) e1 = e;
        float w0 = 1.f / (1.f + __expf(acc[e1] - acc[e0]));
        float w1 = 1.f - w0;
        int p0 = atomicAdd(&cnt[e0], 1);
        rows[e0 * T_TOK + p0] = 2 * t;
        wts[e0 * T_TOK + p0] = w0;
        int p1 = atomicAdd(&cnt[e1], 1);
        rows[e1 * T_TOK + p1] = 2 * t + 1;
        wts[e1 * T_TOK + p1] = w1;
    }
}

// ---------------- generic fp32 -> f16 convert (float4 granules) ----------------
__global__ void f32to16_kernel(const float* __restrict__ src, _Float16* __restrict__ dst) {
    int i = blockIdx.x * blockDim.x + threadIdx.x;
    float4 v = ((const float4*)src)[i];
    union { _Float16 h[4]; uint2 u; } pk;
    pk.h[0] = (_Float16)v.x; pk.h[1] = (_Float16)v.y;
    pk.h[2] = (_Float16)v.z; pk.h[3] = (_Float16)v.w;
    *(uint2*)&dst[(size_t)i * 4] = pk.u;
}

// ================= PATH A: f16 weights, global_load_lds staging =================

__global__ __launch_bounds__(256)
void gateup_a_kernel(const _Float16* __restrict__ Xh,
                     const _Float16* __restrict__ Wgh,
                     const _Float16* __restrict__ Wuh,
                     const int* __restrict__ cnt,
                     const int* __restrict__ rows,
                     const float* __restrict__ wts,
                     _Float16* __restrict__ H) {
    int e = blockIdx.z;
    int c = cnt[e];
    int row0 = blockIdx.y * BM;
    if (row0 >= c) return;
    int col0 = blockIdx.x * BN;

    __shared__ __align__(16) _Float16 As[BM][BK];
    __shared__ __align__(16) _Float16 Bgs[BN][BK];
    __shared__ __align__(16) _Float16 Bus[BN][BK];
    __shared__ int hrow_s[BM];
    __shared__ float w_s[BM];

    int tid = threadIdx.x;
    int lane = tid & 63;
    int wave = tid >> 6;
    int wr = wave >> 1, wc = wave & 1;

    if (tid < BM) {
        int p = row0 + tid;
        if (p < c) { hrow_s[tid] = rows[e * T_TOK + p]; w_s[tid] = wts[e * T_TOK + p]; }
        else       { hrow_s[tid] = -1;                  w_s[tid] = 0.f; }
    }
    __syncthreads();

    // staging mapping: thread tid -> 16B chunk; row = tid>>2, kchunk = tid&3
    int srow = tid >> 2;
    int kch = tid & 3;
    int hr0 = hrow_s[srow], hr1 = hrow_s[srow + 64];
    int tok0 = (hr0 >= 0) ? (hr0 >> 1) : 0;   // invalid rows read token 0; epilogue skips them
    int tok1 = (hr1 >= 0) ? (hr1 >> 1) : 0;

    const _Float16* a0 = Xh + (size_t)tok0 * D_DIM + kch * 8;
    const _Float16* a1 = Xh + (size_t)tok1 * D_DIM + kch * 8;
    const _Float16* g0 = Wgh + ((size_t)e * F_DIM + col0 + srow) * D_DIM + kch * 8;
    const _Float16* g1 = g0 + (size_t)64 * D_DIM;
    const _Float16* u0 = Wuh + ((size_t)e * F_DIM + col0 + srow) * D_DIM + kch * 8;
    const _Float16* u1 = u0 + (size_t)64 * D_DIM;

    _Float16* lA0 = &As[srow][kch * 8];
    _Float16* lA1 = &As[srow + 64][kch * 8];
    _Float16* lG0 = &Bgs[srow][kch * 8];
    _Float16* lG1 = &Bgs[srow + 64][kch * 8];
    _Float16* lU0 = &Bus[srow][kch * 8];
    _Float16* lU1 = &Bus[srow + 64][kch * 8];

    f32x4 accg[4][4], accu[4][4];
#pragma unroll
    for (int i = 0; i < 4; ++i)
#pragma unroll
        for (int j = 0; j < 4; ++j) { accg[i][j] = (f32x4)0.f; accu[i][j] = (f32x4)0.f; }

    int m16 = lane & 15, q8 = (lane >> 4) * 8;

    for (int k0 = 0; k0 < D_DIM; k0 += BK) {
        async_lds16(lA0, a0 + k0);
        async_lds16(lA1, a1 + k0);
        async_lds16(lG0, g0 + k0);
        async_lds16(lG1, g1 + k0);
        async_lds16(lU0, u0 + k0);
        async_lds16(lU1, u1 + k0);
        __syncthreads();

        v8h af[4], bgf[4], buf_[4];
#pragma unroll
        for (int i = 0; i < 4; ++i)
            af[i] = *(const v8h*)&As[wr * 64 + i * 16 + m16][q8];
#pragma unroll
        for (int j = 0; j < 4; ++j) {
            bgf[j]  = *(const v8h*)&Bgs[wc * 64 + j * 16 + m16][q8];
            buf_[j] = *(const v8h*)&Bus[wc * 64 + j * 16 + m16][q8];
        }
#pragma unroll
        for (int i = 0; i < 4; ++i)
#pragma unroll
            for (int j = 0; j < 4; ++j) {
                accg[i][j] = __builtin_amdgcn_mfma_f32_16x16x32_f16(af[i], bgf[j], accg[i][j], 0, 0, 0);
                accu[i][j] = __builtin_amdgcn_mfma_f32_16x16x32_f16(af[i], buf_[j], accu[i][j], 0, 0, 0);
            }
        __syncthreads();
    }

    int q = lane >> 4, cl = lane & 15;
#pragma unroll
    for (int i = 0; i < 4; ++i) {
#pragma unroll
        for (int r4 = 0; r4 < 4; ++r4) {
            int r = wr * 64 + i * 16 + q * 4 + r4;
            int hr = hrow_s[r];
            if (hr < 0) continue;
            float w = w_s[r];
#pragma unroll
            for (int j = 0; j < 4; ++j) {
                int col = col0 + wc * 64 + j * 16 + cl;
                float g = accg[i][j][r4];
                float u = accu[i][j][r4];
                float h = g / (1.f + __expf(-g)) * u * w;
                H[(size_t)hr * F_DIM + col] = (_Float16)h;
            }
        }
    }
}

__global__ __launch_bounds__(256)
void down_a_kernel(const _Float16* __restrict__ H,
                   const _Float16* __restrict__ Wdh,
                   const int* __restrict__ cnt,
                   const int* __restrict__ rows,
                   float* __restrict__ O) {
    int e = blockIdx.z;
    int c = cnt[e];
    int row0 = blockIdx.y * BM;
    if (row0 >= c) return;
    int col0 = blockIdx.x * BN;

    __shared__ __align__(16) _Float16 As[BM][BK];
    __shared__ __align__(16) _Float16 Bs[BN][BK];
    __shared__ int hrow_s[BM];

    int tid = threadIdx.x;
    int lane = tid & 63;
    int wave = tid >> 6;
    int wr = wave >> 1, wc = wave & 1;

    if (tid < BM) {
        int p = row0 + tid;
        hrow_s[tid] = (p < c) ? rows[e * T_TOK + p] : -1;
    }
    __syncthreads();

    int srow = tid >> 2;
    int kch = tid & 3;
    int hr0 = hrow_s[srow], hr1 = hrow_s[srow + 64];
    int r0 = (hr0 >= 0) ? hr0 : 0;
    int r1 = (hr1 >= 0) ? hr1 : 0;

    const _Float16* a0 = H + (size_t)r0 * F_DIM + kch * 8;
    const _Float16* a1 = H + (size_t)r1 * F_DIM + kch * 8;
    const _Float16* b0 = Wdh + ((size_t)e * D_DIM + col0 + srow) * F_DIM + kch * 8;
    const _Float16* b1 = b0 + (size_t)64 * F_DIM;

    _Float16* lA0 = &As[srow][kch * 8];
    _Float16* lA1 = &As[srow + 64][kch * 8];
    _Float16* lB0 = &Bs[srow][kch * 8];
    _Float16* lB1 = &Bs[srow + 64][kch * 8];

    f32x4 acc[4][4];
#pragma unroll
    for (int i = 0; i < 4; ++i)
#pragma unroll
        for (int j = 0; j < 4; ++j) acc[i][j] = (f32x4)0.f;

    int m16 = lane & 15, q8 = (lane >> 4) * 8;

    for (int k0 = 0; k0 < F_DIM; k0 += BK) {
        async_lds16(lA0, a0 + k0);
        async_lds16(lA1, a1 + k0);
        async_lds16(lB0, b0 + k0);
        async_lds16(lB1, b1 + k0);
        __syncthreads();

        v8h af[4], bf[4];
#pragma unroll
        for (int i = 0; i < 4; ++i)
            af[i] = *(const v8h*)&As[wr * 64 + i * 16 + m16][q8];
#pragma unroll
        for (int j = 0; j < 4; ++j)
            bf[j] = *(const v8h*)&Bs[wc * 64 + j * 16 + m16][q8];
#pragma unroll
        for (int i = 0; i < 4; ++i)
#pragma unroll
            for (int j = 0; j < 4; ++j)
                acc[i][j] = __builtin_amdgcn_mfma_f32_16x16x32_f16(af[i], bf[j], acc[i][j], 0, 0, 0);
        __syncthreads();
    }

    int q = lane >> 4, cl = lane & 15;
#pragma unroll
    for (int i = 0; i < 4; ++i) {
#pragma unroll
        for (int r4 = 0; r4 < 4; ++r4) {
            int r = wr * 64 + i * 16 + q * 4 + r4;
            int hr = hrow_s[r];
            if (hr < 0) continue;
#pragma unroll
            for (int j = 0; j < 4; ++j) {
                int col = col0 + wc * 64 + j * 16 + cl;
                O[(size_t)hr * D_DIM + col] = acc[i][j][r4];
            }
        }
    }
}

// ================= PATH B (fallback): fp32 weights, in-flight convert =================

__global__ __launch_bounds__(256)
void gateup_b_kernel(const _Float16* __restrict__ Xh,
                     const float* __restrict__ Wg,
                     const float* __restrict__ Wu,
                     const int* __restrict__ cnt,
                     const int* __restrict__ rows,
                     const float* __restrict__ wts,
                     _Float16* __restrict__ H) {
    int e = blockIdx.z;
    int c = cnt[e];
    int row0 = blockIdx.y * BM;
    if (row0 >= c) return;
    int col0 = blockIdx.x * BN;

    __shared__ __align__(16) _Float16 As[BM][BK];
    __shared__ __align__(16) _Float16 Bgs[BN][BK];
    __shared__ __align__(16) _Float16 Bus[BN][BK];
    __shared__ int hrow_s[BM];
    __shared__ float w_s[BM];

    int tid = threadIdx.x;
    int lane = tid & 63;
    int wave = tid >> 6;
    int wr = wave >> 1, wc = wave & 1;

    if (tid < BM) {
        int p = row0 + tid;
        if (p < c) { hrow_s[tid] = rows[e * T_TOK + p]; w_s[tid] = wts[e * T_TOK + p]; }
        else       { hrow_s[tid] = -1;                  w_s[tid] = 0.f; }
    }
    __syncthreads();

    int ar = tid >> 2;
    int acoff = (tid & 3) * 8;
    int hr0 = hrow_s[ar],  hr1 = hrow_s[ar + 64];
    int tok0 = hr0 >> 1,   tok1 = hr1 >> 1;

    int bn = tid >> 3;
    int bkoff = (tid & 7) * 4;
    const float* wg0 = Wg + ((size_t)e * F_DIM + col0) * D_DIM;
    const float* wu0 = Wu + ((size_t)e * F_DIM + col0) * D_DIM;

    f32x4 accg[4][4], accu[4][4];
#pragma unroll
    for (int i = 0; i < 4; ++i)
#pragma unroll
        for (int j = 0; j < 4; ++j) { accg[i][j] = (f32x4)0.f; accu[i][j] = (f32x4)0.f; }

    int m16 = lane & 15, q8 = (lane >> 4) * 8;

    for (int k0 = 0; k0 < D_DIM; k0 += BK) {
        int4 av0 = make_int4(0, 0, 0, 0), av1 = make_int4(0, 0, 0, 0);
        if (hr0 >= 0) av0 = *(const int4*)&Xh[(size_t)tok0 * D_DIM + k0 + acoff];
        if (hr1 >= 0) av1 = *(const int4*)&Xh[(size_t)tok1 * D_DIM + k0 + acoff];
        *(int4*)&As[ar][acoff] = av0;
        *(int4*)&As[ar + 64][acoff] = av1;
#pragma unroll
        for (int p = 0; p < 4; ++p) {
            int n = p * 32 + bn;
            float4 g4 = *(const float4*)&wg0[(size_t)n * D_DIM + k0 + bkoff];
            float4 u4 = *(const float4*)&wu0[(size_t)n * D_DIM + k0 + bkoff];
            union { _Float16 h[4]; uint2 u; } pg, pu;
            pg.h[0] = (_Float16)g4.x; pg.h[1] = (_Float16)g4.y;
            pg.h[2] = (_Float16)g4.z; pg.h[3] = (_Float16)g4.w;
            pu.h[0] = (_Float16)u4.x; pu.h[1] = (_Float16)u4.y;
            pu.h[2] = (_Float16)u4.z; pu.h[3] = (_Float16)u4.w;
            *(uint2*)&Bgs[n][bkoff] = pg.u;
            *(uint2*)&Bus[n][bkoff] = pu.u;
        }
        __syncthreads();

        v8h af[4], bgf[4], buf_[4];
#pragma unroll
        for (int i = 0; i < 4; ++i)
            af[i] = *(const v8h*)&As[wr * 64 + i * 16 + m16][q8];
#pragma unroll
        for (int j = 0; j < 4; ++j) {
            bgf[j]  = *(const v8h*)&Bgs[wc * 64 + j * 16 + m16][q8];
            buf_[j] = *(const v8h*)&Bus[wc * 64 + j * 16 + m16][q8];
        }
#pragma unroll
        for (int i = 0; i < 4; ++i)
#pragma unroll
            for (int j = 0; j < 4; ++j) {
                accg[i][j] = __builtin_amdgcn_mfma_f32_16x16x32_f16(af[i], bgf[j], accg[i][j], 0, 0, 0);
                accu[i][j] = __builtin_amdgcn_mfma_f32_16x16x32_f16(af[i], buf_[j], accu[i][j], 0, 0, 0);
            }
        __syncthreads();
    }

    int q = lane >> 4, cl = lane & 15;
#pragma unroll
    for (int i = 0; i < 4; ++i) {
#pragma unroll
        for (int r4 = 0; r4 < 4; ++r4) {
            int r = wr * 64 + i * 16 + q * 4 + r4;
            int hr = hrow_s[r];
            if (hr < 0) continue;
            float w = w_s[r];
#pragma unroll
            for (int j = 0; j < 4; ++j) {
                int col = col0 + wc * 64 + j * 16 + cl;
                float g = accg[i][j][r4];
                float u = accu[i][j][r4];
                float h = g / (1.f + __expf(-g)) * u * w;
                H[(size_t)hr * F_DIM + col] = (_Float16)h;
            }
        }
    }
}

__global__ __launch_bounds__(256)
void down_b_kernel(const _Float16* __restrict__ H,
                   const float* __restrict__ Wd,
                   const int* __restrict__ cnt,
                   const int* __restrict__ rows,
                   float* __restrict__ O) {
    int e = blockIdx.z;
    int c = cnt[e];
    int row0 = blockIdx.y * BM;
    if (row0 >= c) return;
    int col0 = blockIdx.x * BN;

    __shared__ __align__(16) _Float16 As[BM][BK];
    __shared__ __align__(16) _Float16 Bs[BN][BK];
    __shared__ int hrow_s[BM];

    int tid = threadIdx.x;
    int lane = tid & 63;
    int wave = tid >> 6;
    int wr = wave >> 1, wc = wave & 1;

    if (tid < BM) {
        int p = row0 + tid;
        hrow_s[tid] = (p < c) ? rows[e * T_TOK + p] : -1;
    }
    __syncthreads();

    int ar = tid >> 2;
    int acoff = (tid & 3) * 8;
    int hr0 = hrow_s[ar], hr1 = hrow_s[ar + 64];

    int bn = tid >> 3;
    int bkoff = (tid & 7) * 4;
    const float* wd0 = Wd + ((size_t)e * D_DIM + col0) * F_DIM;

    f32x4 acc[4][4];
#pragma unroll
    for (int i = 0; i < 4; ++i)
#pragma unroll
        for (int j = 0; j < 4; ++j) acc[i][j] = (f32x4)0.f;

    int m16 = lane & 15, q8 = (lane >> 4) * 8;

    for (int k0 = 0; k0 < F_DIM; k0 += BK) {
        int4 av0 = make_int4(0, 0, 0, 0), av1 = make_int4(0, 0, 0, 0);
        if (hr0 >= 0) av0 = *(const int4*)&H[(size_t)hr0 * F_DIM + k0 + acoff];
        if (hr1 >= 0) av1 = *(const int4*)&H[(size_t)hr1 * F_DIM + k0 + acoff];
        *(int4*)&As[ar][acoff] = av0;
        *(int4*)&As[ar + 64][acoff] = av1;
#pragma unroll
        for (int p = 0; p < 4; ++p) {
            int n = p * 32 + bn;
            float4 b4 = *(const float4*)&wd0[(size_t)n * F_DIM + k0 + bkoff];
            union { _Float16 h[4]; uint2 u; } pb;
            pb.h[0] = (_Float16)b4.x; pb.h[1] = (_Float16)b4.y;
            pb.h[2] = (_Float16)b4.z; pb.h[3] = (_Float16)b4.w;
            *(uint2*)&Bs[n][bkoff] = pb.u;
        }
        __syncthreads();

        v8h af[4], bf[4];
#pragma unroll
        for (int i = 0; i < 4; ++i)
            af[i] = *(const v8h*)&As[wr * 64 + i * 16 + m16][q8];
#pragma unroll
        for (int j = 0; j < 4; ++j)
            bf[j] = *(const v8h*)&Bs[wc * 64 + j * 16 + m16][q8];
#pragma unroll
        for (int i = 0; i < 4; ++i)
#pragma unroll
            for (int j = 0; j < 4; ++j)
                acc[i][j] = __builtin_amdgcn_mfma_f32_16x16x32_f16(af[i], bf[j], acc[i][j], 0, 0, 0);
        __syncthreads();
    }

    int q = lane >> 4, cl = lane & 15;
#pragma unroll
    for (int i = 0; i < 4; ++i) {
#pragma unroll
        for (int r4 = 0; r4 < 4; ++r4) {
            int r = wr * 64 + i * 16 + q * 4 + r4;
            int hr = hrow_s[r];
            if (hr < 0) continue;
#pragma unroll
            for (int j = 0; j < 4; ++j) {
                int col = col0 + wc * 64 + j * 16 + cl;
                O[(size_t)hr * D_DIM + col] = acc[i][j][r4];
            }
        }
    }
}

// ---------------- combine: out[t] = O[2t] + O[2t+1] ----------------
__global__ void combine_kernel(const float* __restrict__ O, float* __restrict__ out) {
    int t = blockIdx.x;
    int d = threadIdx.x;
    const float4* a = (const float4*)(O + (size_t)(2 * t) * D_DIM);
    const float4* b = (const float4*)(O + (size_t)(2 * t + 1) * D_DIM);
    float4 va = a[d], vb = b[d];
    float4 r; r.x = va.x + vb.x; r.y = va.y + vb.y; r.z = va.z + vb.z; r.w = va.w + vb.w;
    ((float4*)(out + (size_t)t * D_DIM))[d] = r;
}

extern "C" void kernel_launch(void* const* d_in, const int* in_sizes, int n_in,
                              void* d_out, int out_size, void* d_ws, size_t ws_size,
                              hipStream_t stream) {
    const float* x     = (const float*)d_in[0];
    const float* Wgate = (const float*)d_in[1];
    const float* Wg    = (const float*)d_in[2];
    const float* Wu    = (const float*)d_in[3];
    const float* Wd    = (const float*)d_in[4];
    float* out = (float*)d_out;

    char* w = (char*)d_ws;
    // common region
    int*      cnt  = (int*)w;                          // 32 B, zeroed below
    int*      rows = (int*)(w + 1024);                 // 256 KB
    float*    wts  = (float*)(w + 263168);             // 256 KB
    _Float16* Xh   = (_Float16*)(w + 525312);          // 16 MB

    // path A extra buffers
    const size_t OFF_WGH = 17302528;                   // 64 MB f16
    const size_t OFF_WUH = 84411392;
    const size_t OFF_WDH = 151520256;
    const size_t OFF_H_A = 218629120;                  // 128 MB
    const size_t OFF_O_A = 352846848;                  // 64 MB
    const size_t NEED_A  = 419955712;                  // ~400.5 MB

    hipMemsetAsync(w, 0, 1024, stream);  // zero expert counters

    router_kernel<<<T_TOK, 64, 0, stream>>>(x, Wgate, cnt, rows, wts);
    f32to16_kernel<<<(T_TOK * D_DIM / 4) / 256, 256, 0, stream>>>(x, Xh);

    if (ws_size >= NEED_A) {
        _Float16* Wgh = (_Float16*)(w + OFF_WGH);
        _Float16* Wuh = (_Float16*)(w + OFF_WUH);
        _Float16* Wdh = (_Float16*)(w + OFF_WDH);
        _Float16* H   = (_Float16*)(w + OFF_H_A);
        float*    O   = (float*)(w + OFF_O_A);

        const int WN4 = (NE * F_DIM * D_DIM / 4);  // 8.4M float4 per tensor
        f32to16_kernel<<<WN4 / 256, 256, 0, stream>>>(Wg, Wgh);
        f32to16_kernel<<<WN4 / 256, 256, 0, stream>>>(Wu, Wuh);
        f32to16_kernel<<<WN4 / 256, 256, 0, stream>>>(Wd, Wdh);

        gateup_a_kernel<<<dim3(F_DIM / BN, T_TOK / BM, NE), 256, 0, stream>>>(
            Xh, Wgh, Wuh, cnt, rows, wts, H);
        down_a_kernel<<<dim3(D_DIM / BN, T_TOK / BM, NE), 256, 0, stream>>>(
            H, Wdh, cnt, rows, O);
        combine_kernel<<<T_TOK, 256, 0, stream>>>(O, out);
    } else {
        _Float16* H = (_Float16*)(w + 17302528);       // 128 MB
        float*    O = (float*)(w + 151520256);         // 64 MB
        gateup_b_kernel<<<dim3(F_DIM / BN, T_TOK / BM, NE), 256, 0, stream>>>(
            Xh, Wg, Wu, cnt, rows, wts, H);
        down_b_kernel<<<dim3(D_DIM / BN, T_TOK / BM, NE), 256, 0, stream>>>(
            H, Wd, cnt, rows, O);
        combine_kernel<<<T_TOK, 256, 0, stream>>>(O, out);
    }
}

// Round 3
// 1227.972 us; speedup vs baseline: 1.3060x; 1.3060x over previous
//
#include <hip/hip_runtime.h>
#include <hip/hip_bf16.h>

#define T_TOK 8192
#define D_DIM 1024
#define F_DIM 4096
#define NE 8

#define BM 128
#define BK 32

typedef _Float16 v8h __attribute__((ext_vector_type(8)));
typedef float f32x4 __attribute__((ext_vector_type(4)));

__device__ __forceinline__ void async_lds16(void* lds, const void* g) {
    __builtin_amdgcn_global_load_lds(
        (const __attribute__((address_space(1))) void*)g,
        (__attribute__((address_space(3))) void*)lds,
        16, 0, 0);
}

// ---------------- router: logits -> top2 -> scatter ----------------
__global__ void router_kernel(const float* __restrict__ x,
                              const float* __restrict__ Wgate,
                              int* __restrict__ cnt,
                              int* __restrict__ rows,
                              float* __restrict__ wts) {
    int t = blockIdx.x;
    int lane = threadIdx.x;
    const float* xr = x + (size_t)t * D_DIM;
    float acc[NE];
#pragma unroll
    for (int e = 0; e < NE; ++e) acc[e] = 0.f;
#pragma unroll
    for (int i = 0; i < D_DIM / 64; ++i) {
        int d = i * 64 + lane;
        float xv = xr[d];
#pragma unroll
        for (int e = 0; e < NE; ++e) acc[e] += xv * Wgate[e * D_DIM + d];
    }
#pragma unroll
    for (int off = 32; off > 0; off >>= 1) {
#pragma unroll
        for (int e = 0; e < NE; ++e) acc[e] += __shfl_xor(acc[e], off, 64);
    }
    if (lane == 0) {
        int e0 = 0;
#pragma unroll
        for (int e = 1; e < NE; ++e) if (acc[e] > acc[e0]) e0 = e;
        int e1 = (e0 == 0) ? 1 : 0;
#pragma unroll
        for (int e = 0; e < NE; ++e) if (e != e0 && acc[e] > acc[e1]) e1 = e;
        float w0 = 1.f / (1.f + __expf(acc[e1] - acc[e0]));
        float w1 = 1.f - w0;
        int p0 = atomicAdd(&cnt[e0], 1);
        rows[e0 * T_TOK + p0] = 2 * t;
        wts[e0 * T_TOK + p0] = w0;
        int p1 = atomicAdd(&cnt[e1], 1);
        rows[e1 * T_TOK + p1] = 2 * t + 1;
        wts[e1 * T_TOK + p1] = w1;
    }
}

// ---------------- generic fp32 -> f16 convert (float4 granules) ----------------
__global__ void f32to16_kernel(const float* __restrict__ src, _Float16* __restrict__ dst) {
    int i = blockIdx.x * blockDim.x + threadIdx.x;
    float4 v = ((const float4*)src)[i];
    union { _Float16 h[4]; uint2 u; } pk;
    pk.h[0] = (_Float16)v.x; pk.h[1] = (_Float16)v.y;
    pk.h[2] = (_Float16)v.z; pk.h[3] = (_Float16)v.w;
    *(uint2*)&dst[(size_t)i * 4] = pk.u;
}

// ========== gateup: paired-column layout, one 4x4 acc per wave (64 AGPR) ==========
// B tile rows 0..63  = Wg cols [col0, col0+64)
// B tile rows 64..127= Wu cols [col0, col0+64)
// wave (wr, wc=0) -> gate acc, wave (wr, wc=1) -> up acc, same (row, col) range.
// Epilogue: gate waves write silu(g)*w to LDS exchange (stride 66 = 2-way banks,
// free per m136); up waves multiply by u and store H.
__global__ __launch_bounds__(256, 2)
void gateup_kernel(const _Float16* __restrict__ Xh,
                   const _Float16* __restrict__ Wgh,
                   const _Float16* __restrict__ Wuh,
                   const int* __restrict__ cnt,
                   const int* __restrict__ rows,
                   const float* __restrict__ wts,
                   _Float16* __restrict__ H) {
    int e = blockIdx.z;
    int c = cnt[e];
    int row0 = blockIdx.y * BM;
    if (row0 >= c) return;
    int col0 = blockIdx.x * 64;

    // smem union: [As 128x32 f16 | Bs 128x32 f16] (16 KB) overlaid by ex[128][66] f32 (33.8 KB)
    __shared__ __align__(16) char smem[128 * 66 * 4];
    _Float16 (*As)[BK] = (_Float16(*)[BK])smem;
    _Float16 (*Bs)[BK] = (_Float16(*)[BK])(smem + BM * BK * 2);
    float (*ex)[66] = (float(*)[66])smem;
    __shared__ int hrow_s[BM];
    __shared__ float w_s[BM];

    int tid = threadIdx.x;
    int lane = tid & 63;
    int wave = tid >> 6;
    int wr = wave >> 1, wc = wave & 1;

    if (tid < BM) {
        int p = row0 + tid;
        if (p < c) { hrow_s[tid] = rows[e * T_TOK + p]; w_s[tid] = wts[e * T_TOK + p]; }
        else       { hrow_s[tid] = -1;                  w_s[tid] = 0.f; }
    }
    __syncthreads();

    int srow = tid >> 2;          // 0..63
    int kch = tid & 3;            // 16B chunk within BK
    int hr0 = hrow_s[srow], hr1 = hrow_s[srow + 64];
    int tok0 = (hr0 >= 0) ? (hr0 >> 1) : 0;
    int tok1 = (hr1 >= 0) ? (hr1 >> 1) : 0;

    const _Float16* a0 = Xh + (size_t)tok0 * D_DIM + kch * 8;
    const _Float16* a1 = Xh + (size_t)tok1 * D_DIM + kch * 8;
    const _Float16* bg = Wgh + ((size_t)e * F_DIM + col0 + srow) * D_DIM + kch * 8;
    const _Float16* bu = Wuh + ((size_t)e * F_DIM + col0 + srow) * D_DIM + kch * 8;

    _Float16* lA0 = &As[srow][kch * 8];
    _Float16* lA1 = &As[srow + 64][kch * 8];
    _Float16* lB0 = &Bs[srow][kch * 8];
    _Float16* lB1 = &Bs[srow + 64][kch * 8];

    f32x4 acc[4][4];
#pragma unroll
    for (int i = 0; i < 4; ++i)
#pragma unroll
        for (int j = 0; j < 4; ++j) acc[i][j] = (f32x4)0.f;

    int m16 = lane & 15, q8 = (lane >> 4) * 8;

    for (int k0 = 0; k0 < D_DIM; k0 += BK) {
        async_lds16(lA0, a0 + k0);
        async_lds16(lA1, a1 + k0);
        async_lds16(lB0, bg + k0);
        async_lds16(lB1, bu + k0);
        __syncthreads();

        v8h af[4], bf[4];
#pragma unroll
        for (int i = 0; i < 4; ++i)
            af[i] = *(const v8h*)&As[wr * 64 + i * 16 + m16][q8];
#pragma unroll
        for (int j = 0; j < 4; ++j)
            bf[j] = *(const v8h*)&Bs[wc * 64 + j * 16 + m16][q8];
#pragma unroll
        for (int i = 0; i < 4; ++i)
#pragma unroll
            for (int j = 0; j < 4; ++j)
                acc[i][j] = __builtin_amdgcn_mfma_f32_16x16x32_f16(af[i], bf[j], acc[i][j], 0, 0, 0);
        __syncthreads();
    }

    int q = lane >> 4, cl = lane & 15;
    if (wc == 0) {
        // gate waves: silu(g) * w -> exchange buffer
#pragma unroll
        for (int i = 0; i < 4; ++i)
#pragma unroll
            for (int r4 = 0; r4 < 4; ++r4) {
                int r = wr * 64 + i * 16 + q * 4 + r4;
                float w = w_s[r];
#pragma unroll
                for (int j = 0; j < 4; ++j) {
                    float g = acc[i][j][r4];
                    ex[r][j * 16 + cl] = g / (1.f + __expf(-g)) * w;
                }
            }
    }
    __syncthreads();
    if (wc == 1) {
        // up waves: h = ex * u -> H
#pragma unroll
        for (int i = 0; i < 4; ++i)
#pragma unroll
            for (int r4 = 0; r4 < 4; ++r4) {
                int r = wr * 64 + i * 16 + q * 4 + r4;
                int hr = hrow_s[r];
                if (hr < 0) continue;
#pragma unroll
                for (int j = 0; j < 4; ++j) {
                    float h = ex[r][j * 16 + cl] * acc[i][j][r4];
                    H[(size_t)hr * F_DIM + col0 + j * 16 + cl] = (_Float16)h;
                }
            }
    }
}

// ---------------- down GEMM: H @ Wd^T -> O (fp32, slot-indexed) ----------------
__global__ __launch_bounds__(256, 2)
void down_kernel(const _Float16* __restrict__ H,
                 const _Float16* __restrict__ Wdh,
                 const int* __restrict__ cnt,
                 const int* __restrict__ rows,
                 float* __restrict__ O) {
    int e = blockIdx.z;
    int c = cnt[e];
    int row0 = blockIdx.y * BM;
    if (row0 >= c) return;
    int col0 = blockIdx.x * 128;

    __shared__ __align__(16) _Float16 As[BM][BK];
    __shared__ __align__(16) _Float16 Bs[128][BK];
    __shared__ int hrow_s[BM];

    int tid = threadIdx.x;
    int lane = tid & 63;
    int wave = tid >> 6;
    int wr = wave >> 1, wc = wave & 1;

    if (tid < BM) {
        int p = row0 + tid;
        hrow_s[tid] = (p < c) ? rows[e * T_TOK + p] : -1;
    }
    __syncthreads();

    int srow = tid >> 2;
    int kch = tid & 3;
    int hr0 = hrow_s[srow], hr1 = hrow_s[srow + 64];
    int r0 = (hr0 >= 0) ? hr0 : 0;
    int r1 = (hr1 >= 0) ? hr1 : 0;

    const _Float16* a0 = H + (size_t)r0 * F_DIM + kch * 8;
    const _Float16* a1 = H + (size_t)r1 * F_DIM + kch * 8;
    const _Float16* b0 = Wdh + ((size_t)e * D_DIM + col0 + srow) * F_DIM + kch * 8;
    const _Float16* b1 = b0 + (size_t)64 * F_DIM;

    _Float16* lA0 = &As[srow][kch * 8];
    _Float16* lA1 = &As[srow + 64][kch * 8];
    _Float16* lB0 = &Bs[srow][kch * 8];
    _Float16* lB1 = &Bs[srow + 64][kch * 8];

    f32x4 acc[4][4];
#pragma unroll
    for (int i = 0; i < 4; ++i)
#pragma unroll
        for (int j = 0; j < 4; ++j) acc[i][j] = (f32x4)0.f;

    int m16 = lane & 15, q8 = (lane >> 4) * 8;

    for (int k0 = 0; k0 < F_DIM; k0 += BK) {
        async_lds16(lA0, a0 + k0);
        async_lds16(lA1, a1 + k0);
        async_lds16(lB0, b0 + k0);
        async_lds16(lB1, b1 + k0);
        __syncthreads();

        v8h af[4], bf[4];
#pragma unroll
        for (int i = 0; i < 4; ++i)
            af[i] = *(const v8h*)&As[wr * 64 + i * 16 + m16][q8];
#pragma unroll
        for (int j = 0; j < 4; ++j)
            bf[j] = *(const v8h*)&Bs[wc * 64 + j * 16 + m16][q8];
#pragma unroll
        for (int i = 0; i < 4; ++i)
#pragma unroll
            for (int j = 0; j < 4; ++j)
                acc[i][j] = __builtin_amdgcn_mfma_f32_16x16x32_f16(af[i], bf[j], acc[i][j], 0, 0, 0);
        __syncthreads();
    }

    int q = lane >> 4, cl = lane & 15;
#pragma unroll
    for (int i = 0; i < 4; ++i) {
#pragma unroll
        for (int r4 = 0; r4 < 4; ++r4) {
            int r = wr * 64 + i * 16 + q * 4 + r4;
            int hr = hrow_s[r];
            if (hr < 0) continue;
#pragma unroll
            for (int j = 0; j < 4; ++j) {
                int col = col0 + wc * 64 + j * 16 + cl;
                O[(size_t)hr * D_DIM + col] = acc[i][j][r4];
            }
        }
    }
}

// ---------------- combine: out[t] = O[2t] + O[2t+1] ----------------
__global__ void combine_kernel(const float* __restrict__ O, float* __restrict__ out) {
    int t = blockIdx.x;
    int d = threadIdx.x;
    const float4* a = (const float4*)(O + (size_t)(2 * t) * D_DIM);
    const float4* b = (const float4*)(O + (size_t)(2 * t + 1) * D_DIM);
    float4 va = a[d], vb = b[d];
    float4 r; r.x = va.x + vb.x; r.y = va.y + vb.y; r.z = va.z + vb.z; r.w = va.w + vb.w;
    ((float4*)(out + (size_t)t * D_DIM))[d] = r;
}

extern "C" void kernel_launch(void* const* d_in, const int* in_sizes, int n_in,
                              void* d_out, int out_size, void* d_ws, size_t ws_size,
                              hipStream_t stream) {
    const float* x     = (const float*)d_in[0];
    const float* Wgate = (const float*)d_in[1];
    const float* Wg    = (const float*)d_in[2];
    const float* Wu    = (const float*)d_in[3];
    const float* Wd    = (const float*)d_in[4];
    float* out = (float*)d_out;

    char* w = (char*)d_ws;
    int*      cnt  = (int*)w;                          // 32 B, zeroed below
    int*      rows = (int*)(w + 1024);                 // 256 KB
    float*    wts  = (float*)(w + 263168);             // 256 KB
    _Float16* Xh   = (_Float16*)(w + 525312);          // 16 MB

    const size_t OFF_WGH = 17302528;                   // 64 MB f16
    const size_t OFF_WUH = 84411392;
    const size_t OFF_WDH = 151520256;
    const size_t OFF_H   = 218629120;                  // 128 MB
    const size_t OFF_O   = 352846848;                  // 64 MB

    _Float16* Wgh = (_Float16*)(w + OFF_WGH);
    _Float16* Wuh = (_Float16*)(w + OFF_WUH);
    _Float16* Wdh = (_Float16*)(w + OFF_WDH);
    _Float16* H   = (_Float16*)(w + OFF_H);
    float*    O   = (float*)(w + OFF_O);

    hipMemsetAsync(w, 0, 1024, stream);  // zero expert counters

    router_kernel<<<T_TOK, 64, 0, stream>>>(x, Wgate, cnt, rows, wts);
    f32to16_kernel<<<(T_TOK * D_DIM / 4) / 256, 256, 0, stream>>>(x, Xh);

    const int WN4 = (NE * F_DIM * D_DIM / 4);
    f32to16_kernel<<<WN4 / 256, 256, 0, stream>>>(Wg, Wgh);
    f32to16_kernel<<<WN4 / 256, 256, 0, stream>>>(Wu, Wuh);
    f32to16_kernel<<<WN4 / 256, 256, 0, stream>>>(Wd, Wdh);

    gateup_kernel<<<dim3(F_DIM / 64, T_TOK / BM, NE), 256, 0, stream>>>(
        Xh, Wgh, Wuh, cnt, rows, wts, H);
    down_kernel<<<dim3(D_DIM / 128, T_TOK / BM, NE), 256, 0, stream>>>(
        H, Wdh, cnt, rows, O);
    combine_kernel<<<T_TOK, 256, 0, stream>>>(O, out);
}